// Round 5
// baseline (179.846 us; speedup 1.0000x reference)
//
#include <hip/hip_runtime.h>
#include <math.h>

namespace {
constexpr int kN    = 8192;
constexpr int kC    = 256;
constexpr int kM    = 32;
constexpr int kTAB  = 3025;
constexpr int kRowsTotal = 2 * kN;  // B*N = 16384
constexpr float kScale = 0.17677669529663687f;  // 32^-0.5
}

typedef __attribute__((ext_vector_type(8))) short bf16x8;
typedef __attribute__((ext_vector_type(4))) float f32x4;

__device__ __forceinline__ unsigned short f2bf(float f) {
  unsigned int u = __float_as_uint(f);
  u += 0x7fffu + ((u >> 16) & 1u);   // round-to-nearest-even
  return (unsigned short)(u >> 16);
}
__device__ __forceinline__ float bflo(unsigned int u) {
  return __uint_as_float(u << 16);
}
__device__ __forceinline__ float bfhi(unsigned int u) {
  return __uint_as_float(u & 0xffff0000u);
}

#define GLOAD16(g, l)                                                   \
  __builtin_amdgcn_global_load_lds(                                     \
      (const __attribute__((address_space(1))) void*)(g),               \
      (__attribute__((address_space(3))) void*)(l), 16, 0, 0)

// ---------------- LayerNorm -> bf16 ----------------
__global__ __launch_bounds__(256) void ln_bf16_kernel(
    const float* __restrict__ x, const float* __restrict__ w,
    const float* __restrict__ b, unsigned short* __restrict__ o) {
  int row = blockIdx.x;
  int t = threadIdx.x;
  float v = x[(size_t)row * kC + t];
  float s = v, s2 = v * v;
#pragma unroll
  for (int off = 32; off > 0; off >>= 1) {
    s  += __shfl_down(s, off, 64);
    s2 += __shfl_down(s2, off, 64);
  }
  __shared__ float rs[4], rs2[4];
  __shared__ float mu_s, rstd_s;
  if ((t & 63) == 0) { rs[t >> 6] = s; rs2[t >> 6] = s2; }
  __syncthreads();
  if (t == 0) {
    float tot  = rs[0] + rs[1] + rs[2] + rs[3];
    float tot2 = rs2[0] + rs2[1] + rs2[2] + rs2[3];
    float mu  = tot * (1.0f / kC);
    float var = tot2 * (1.0f / kC) - mu * mu;
    mu_s = mu;
    rstd_s = rsqrtf(var + 1e-5f);
  }
  __syncthreads();
  o[(size_t)row * kC + t] = f2bf((v - mu_s) * rstd_s * w[t] + b[t]);
}

// ---------------- PE table ----------------
__global__ __launch_bounds__(256) void pe_kernel(const float* __restrict__ tab,
                                                 const float* __restrict__ pw,
                                                 const float* __restrict__ pb,
                                                 float* __restrict__ outp) {
  int i = blockIdx.x * 256 + threadIdx.x;
  if (i >= kTAB * 8) return;
  int r = i >> 3, h = i & 7;
  float acc = pb[h];
#pragma unroll
  for (int f = 0; f < 5; ++f) acc += tab[r * 5 + f] * pw[h * 5 + f];
  outp[i] = acc;
}

// ---------------- cast weights to bf16 (+ concat qkv bias) ----------------
__global__ __launch_bounds__(256) void cast_weights_kernel(
    const float* __restrict__ qw, const float* __restrict__ kvw,
    const float* __restrict__ pjw, const float* __restrict__ f1w,
    const float* __restrict__ f2w, const float* __restrict__ qb,
    const float* __restrict__ kvb, unsigned short* __restrict__ wqkv,
    unsigned short* __restrict__ wproj, unsigned short* __restrict__ wfc1,
    unsigned short* __restrict__ wfc2, float* __restrict__ bqkv) {
  int i = blockIdx.x * 256 + threadIdx.x;
  if (i < 65536)       wqkv[i]            = f2bf(qw[i]);
  else if (i < 196608) wqkv[i]            = f2bf(kvw[i - 65536]);
  else if (i < 262144) wproj[i - 196608]  = f2bf(pjw[i - 196608]);
  else if (i < 393216) wfc1[i - 262144]   = f2bf(f1w[i - 262144]);
  else if (i < 524288) wfc2[i - 393216]   = f2bf(f2w[i - 393216]);
  else if (i < 524544) bqkv[i - 524288]   = qb[i - 524288];
  else if (i < 525056) bqkv[i - 524288]   = kvb[i - 524544];
}

// ---------------- bf16 MFMA GEMM: C = A[M,K] @ W[N,K]^T, fused epilogues -----
template <int EPI, int KDIM>
__global__ __launch_bounds__(256) void mfma_gemm(
    const unsigned short* __restrict__ A, const unsigned short* __restrict__ Wt,
    const float* __restrict__ bias, void* __restrict__ o1,
    unsigned short* __restrict__ o2, unsigned short* __restrict__ o3,
    const float* __restrict__ res) {
  __shared__ alignas(16) unsigned short As[128 * 32];
  __shared__ alignas(16) unsigned short Bs[128 * 32];
  int t = threadIdx.x;
  int w = t >> 6, l = t & 63;
  int wr = w >> 1, wc = w & 1;
  int bm = blockIdx.x * 128, bn = blockIdx.y * 128;

  f32x4 acc[4][4] = {};

  const size_t aoff = (size_t)(bm + w * 32 + (l >> 2)) * KDIM + (l & 3) * 8;
  const size_t boff = (size_t)(bn + w * 32 + (l >> 2)) * KDIM + (l & 3) * 8;
  unsigned short* AsW = As + w * 1024 + l * 8;
  unsigned short* BsW = Bs + w * 1024 + l * 8;

  const int lr = l & 15, lk = l >> 4;

  for (int k0 = 0; k0 < KDIM; k0 += 32) {
    GLOAD16(A + aoff + k0, AsW);
    GLOAD16(A + aoff + k0 + (size_t)16 * KDIM, AsW + 512);
    GLOAD16(Wt + boff + k0, BsW);
    GLOAD16(Wt + boff + k0 + (size_t)16 * KDIM, BsW + 512);
    __syncthreads();
    bf16x8 af[4], bf[4];
#pragma unroll
    for (int mi = 0; mi < 4; ++mi)
      af[mi] = *(const bf16x8*)(As + (wr * 64 + mi * 16 + lr) * 32 + lk * 8);
#pragma unroll
    for (int ni = 0; ni < 4; ++ni)
      bf[ni] = *(const bf16x8*)(Bs + (wc * 64 + ni * 16 + lr) * 32 + lk * 8);
#pragma unroll
    for (int mi = 0; mi < 4; ++mi)
#pragma unroll
      for (int ni = 0; ni < 4; ++ni)
        acc[mi][ni] = __builtin_amdgcn_mfma_f32_16x16x32_bf16(
            af[mi], bf[ni], acc[mi][ni], 0, 0, 0);
    __syncthreads();
  }

#pragma unroll
  for (int mi = 0; mi < 4; ++mi) {
#pragma unroll
    for (int ni = 0; ni < 4; ++ni) {
      int row0 = bm + wr * 64 + mi * 16 + lk * 4;
      int col  = bn + wc * 64 + ni * 16 + lr;
      float bv = bias[col];
#pragma unroll
      for (int j = 0; j < 4; ++j) {
        int r = row0 + j;
        float x = acc[mi][ni][j] + bv;
        if constexpr (EPI == 0) {
          if (col < 256) {
            ((float*)o1)[(size_t)r * 256 + col] = x * kScale;
          } else {
            int c = col - 256;
            int h = c >> 6, sbit = (c >> 5) & 1, ch = c & 31;
            unsigned short* dst = sbit ? o3 : o2;
            dst[(size_t)r * 256 + h * 32 + ch] = f2bf(x);
          }
        } else if constexpr (EPI == 1) {
          ((float*)o1)[(size_t)r * 256 + col] = res[(size_t)r * 256 + col] + x;
        } else if constexpr (EPI == 2) {
          float g = 0.5f * x * (1.0f + erff(x * 0.70710678118654752f));
          ((unsigned short*)o1)[(size_t)r * 512 + col] = f2bf(g);
        } else {
          ((float*)o1)[(size_t)r * 256 + col] = res[(size_t)r * 256 + col] + x;
        }
      }
    }
  }
}

// ---------------- Attention: one WAVE per token, fully barrier-free -----------
// lane l: h = l>>3 (head), g = l&7.
// QK: 4 logits per lane (m = g+8*mi). PV: channels c = g*4..+3 of head h.
// All gathers issued up-front: idx -> K(16 uint4) -> V(32 uint2). K issued
// before V so QK's waitcnt doesn't drain the V queue (oldest-first semantics).
__global__ __launch_bounds__(256) void attn_kernel(
    const float* __restrict__ q, const unsigned short* __restrict__ k,
    const unsigned short* __restrict__ v, const int* __restrict__ member_idx,
    const int* __restrict__ pe_idx, const float* __restrict__ cmask,
    const float* __restrict__ pe_full, const float* __restrict__ blank_k,
    const float* __restrict__ blank_v, unsigned short* __restrict__ outp) {
  int t = threadIdx.x;
  int w = t >> 6, l = t & 63;
  int row = blockIdx.x * 4 + w;
  int b = row >> 13;  // N = 8192
  const size_t kvbase = (size_t)b * kN;
  const int h = l >> 3, g = l & 7;
  const int grp = l & 56;  // h*8

  // ---- member indices (1 latency round; 8-way dup merged by coalescer) ----
  int idxv[4];
#pragma unroll
  for (int mi = 0; mi < 4; ++mi)
    idxv[mi] = member_idx[(size_t)row * 32 + g + mi * 8];

  // ---- K gather: 16 independent uint4 loads (issued first) ----
  uint4 kvr[4][4];
#pragma unroll
  for (int mi = 0; mi < 4; ++mi) {
    const uint4* kr = (const uint4*)(k + (kvbase + idxv[mi]) * 256 + h * 32);
#pragma unroll
    for (int j = 0; j < 4; ++j) kvr[mi][j] = kr[j];
  }

  // ---- V gather: 32 independent uint2 loads (in flight through QK+softmax) --
  uint2 vv[32];
#pragma unroll
  for (int m = 0; m < 32; ++m) {
    int im = __shfl(idxv[m >> 3], grp | (m & 7), 64);
    vv[m] = *(const uint2*)(v + (kvbase + im) * 256 + h * 32 + g * 4);
  }

  // ---- q head slice + bias terms ----
  float4 qv[8];
#pragma unroll
  for (int i = 0; i < 8; ++i)
    qv[i] = *(const float4*)(q + (size_t)row * 256 + h * 32 + i * 4);

  float mkv[4], pev[4];
#pragma unroll
  for (int mi = 0; mi < 4; ++mi) {
    int m = g + mi * 8;
    mkv[mi] = (1.0f - cmask[(size_t)row * 32 + m]) * -100.0f;
    pev[mi] = pe_full[(size_t)pe_idx[(size_t)row * 32 + m] * 8 + h];
  }

  // ---- QK logits ----
  float lg[4];
#pragma unroll
  for (int mi = 0; mi < 4; ++mi) {
    float acc = 0.f;
#pragma unroll
    for (int j = 0; j < 4; ++j) {
      uint4 u = kvr[mi][j];
      acc = fmaf(qv[2 * j].x, bflo(u.x), acc);
      acc = fmaf(qv[2 * j].y, bfhi(u.x), acc);
      acc = fmaf(qv[2 * j].z, bflo(u.y), acc);
      acc = fmaf(qv[2 * j].w, bfhi(u.y), acc);
      acc = fmaf(qv[2 * j + 1].x, bflo(u.z), acc);
      acc = fmaf(qv[2 * j + 1].y, bfhi(u.z), acc);
      acc = fmaf(qv[2 * j + 1].z, bflo(u.w), acc);
      acc = fmaf(qv[2 * j + 1].w, bfhi(u.w), acc);
    }
    lg[mi] = acc + mkv[mi] + pev[mi];
  }

  // ---- blank logit (identical across the 8-lane head group) ----
  float bl = 0.f;
#pragma unroll
  for (int i = 0; i < 8; ++i) {
    float4 bk = *(const float4*)(blank_k + h * 32 + i * 4);
    bl += qv[i].x * bk.x + qv[i].y * bk.y + qv[i].z * bk.z + qv[i].w * bk.w;
  }
  bl = fminf(fmaxf(bl, -5.0f), 5.0f);

  // ---- wave-parallel softmax over 33 within each 8-lane head group ----
  float mx = fmaxf(fmaxf(lg[0], lg[1]), fmaxf(lg[2], lg[3]));
#pragma unroll
  for (int d = 1; d < 8; d <<= 1) mx = fmaxf(mx, __shfl_xor(mx, d, 64));
  mx = fmaxf(mx, bl);
  float e[4], s = 0.f;
#pragma unroll
  for (int mi = 0; mi < 4; ++mi) { e[mi] = __expf(lg[mi] - mx); s += e[mi]; }
#pragma unroll
  for (int d = 1; d < 8; d <<= 1) s += __shfl_xor(s, d, 64);
  float eb = __expf(bl - mx);
  s += eb;
  float inv = __builtin_amdgcn_rcpf(s);
  float awv[4];
#pragma unroll
  for (int mi = 0; mi < 4; ++mi) awv[mi] = e[mi] * inv;
  float abv = eb * inv;

  // ---- PV from prefetched V regs, weights broadcast via shfl ----
  float a0 = 0.f, a1 = 0.f, a2 = 0.f, a3 = 0.f;
#pragma unroll
  for (int m = 0; m < 32; ++m) {
    float a = __shfl(awv[m >> 3], grp | (m & 7), 64);
    a0 = fmaf(a, bflo(vv[m].x), a0);
    a1 = fmaf(a, bfhi(vv[m].x), a1);
    a2 = fmaf(a, bflo(vv[m].y), a2);
    a3 = fmaf(a, bfhi(vv[m].y), a3);
  }
  {
    float4 bv = *(const float4*)(blank_v + h * 32 + g * 4);
    a0 = fmaf(abv, bv.x, a0);
    a1 = fmaf(abv, bv.y, a1);
    a2 = fmaf(abv, bv.z, a2);
    a3 = fmaf(abv, bv.w, a3);
  }
  uint2 o;
  o.x = ((unsigned int)f2bf(a1) << 16) | f2bf(a0);
  o.y = ((unsigned int)f2bf(a3) << 16) | f2bf(a2);
  *(uint2*)(outp + (size_t)row * 256 + h * 32 + g * 4) = o;
}

extern "C" void kernel_launch(void* const* d_in, const int* in_sizes, int n_in,
                              void* d_out, int out_size, void* d_ws, size_t ws_size,
                              hipStream_t stream) {
  const float* feat       = (const float*)d_in[0];
  const int*   member_idx = (const int*)d_in[1];
  const float* cmask      = (const float*)d_in[2];
  const int*   pe_idx     = (const int*)d_in[3];
  const float* pre_table  = (const float*)d_in[5];
  const float* n1w        = (const float*)d_in[6];
  const float* n1b        = (const float*)d_in[7];
  const float* q_w        = (const float*)d_in[8];
  const float* q_b        = (const float*)d_in[9];
  const float* kv_w       = (const float*)d_in[10];
  const float* kv_b       = (const float*)d_in[11];
  const float* blank_k    = (const float*)d_in[12];
  const float* blank_v    = (const float*)d_in[13];
  const float* pe_w       = (const float*)d_in[14];
  const float* pe_b       = (const float*)d_in[15];
  const float* proj_w     = (const float*)d_in[16];
  const float* proj_b     = (const float*)d_in[17];
  const float* n2w        = (const float*)d_in[18];
  const float* n2b        = (const float*)d_in[19];
  const float* fc1_w      = (const float*)d_in[20];
  const float* fc1_b      = (const float*)d_in[21];
  const float* fc2_w      = (const float*)d_in[22];
  const float* fc2_b      = (const float*)d_in[23];

  float* out = (float*)d_out;
  unsigned char* ws = (unsigned char*)d_ws;

  unsigned short* xln   = (unsigned short*)(ws + 0);           // 8 MB, later attn_out
  float*          q_buf = (float*)(ws + 8388608);              // 16 MB, later yln
  unsigned short* k_buf = (unsigned short*)(ws + 25165824);    // 8 MB \ later h1 (16MB)
  unsigned short* v_buf = (unsigned short*)(ws + 33554432);    // 8 MB /
  unsigned short* wqkv  = (unsigned short*)(ws + 41943040);    // 384 KB
  unsigned short* wproj = (unsigned short*)(ws + 42336256);    // 128 KB
  unsigned short* wfc1  = (unsigned short*)(ws + 42467328);    // 256 KB
  unsigned short* wfc2  = (unsigned short*)(ws + 42729472);    // 256 KB
  float*          bqkv  = (float*)(ws + 42991616);             // 3 KB
  float*          pe_buf= (float*)(ws + 42994688);             // ~97 KB
  unsigned short* attn_out = xln;
  unsigned short* yln   = (unsigned short*)q_buf;
  unsigned short* h1    = k_buf;

  cast_weights_kernel<<<2052, 256, 0, stream>>>(
      q_w, kv_w, proj_w, fc1_w, fc2_w, q_b, kv_b, wqkv, wproj, wfc1, wfc2, bqkv);
  pe_kernel<<<(kTAB * 8 + 255) / 256, 256, 0, stream>>>(pre_table, pe_w, pe_b, pe_buf);
  ln_bf16_kernel<<<kRowsTotal, 256, 0, stream>>>(feat, n1w, n1b, xln);

  mfma_gemm<0, 256><<<dim3(kRowsTotal / 128, 6), 256, 0, stream>>>(
      xln, wqkv, bqkv, q_buf, k_buf, v_buf, nullptr);

  attn_kernel<<<kRowsTotal / 4, 256, 0, stream>>>(
      q_buf, k_buf, v_buf, member_idx, pe_idx, cmask, pe_buf, blank_k, blank_v,
      attn_out);

  mfma_gemm<1, 256><<<dim3(kRowsTotal / 128, 2), 256, 0, stream>>>(
      attn_out, wproj, proj_b, out, nullptr, nullptr, feat);

  ln_bf16_kernel<<<kRowsTotal, 256, 0, stream>>>(out, n2w, n2b, yln);

  mfma_gemm<2, 256><<<dim3(kRowsTotal / 128, 4), 256, 0, stream>>>(
      yln, wfc1, fc1_b, h1, nullptr, nullptr, nullptr);

  mfma_gemm<3, 512><<<dim3(kRowsTotal / 128, 2), 256, 0, stream>>>(
      h1, wfc2, fc2_b, out, nullptr, nullptr, out);
}

// Round 6
// 177.777 us; speedup vs baseline: 1.0116x; 1.0116x over previous
//
#include <hip/hip_runtime.h>
#include <math.h>

namespace {
constexpr int kN    = 8192;
constexpr int kC    = 256;
constexpr int kM    = 32;
constexpr int kTAB  = 3025;
constexpr int kRowsTotal = 2 * kN;  // B*N = 16384
constexpr float kScale = 0.17677669529663687f;  // 32^-0.5
}

typedef __attribute__((ext_vector_type(8))) short bf16x8;
typedef __attribute__((ext_vector_type(4))) float f32x4;

__device__ __forceinline__ unsigned short f2bf(float f) {
  unsigned int u = __float_as_uint(f);
  u += 0x7fffu + ((u >> 16) & 1u);   // round-to-nearest-even
  return (unsigned short)(u >> 16);
}
__device__ __forceinline__ float bflo(unsigned int u) {
  return __uint_as_float(u << 16);
}
__device__ __forceinline__ float bfhi(unsigned int u) {
  return __uint_as_float(u & 0xffff0000u);
}

#define GLOAD16(g, l)                                                   \
  __builtin_amdgcn_global_load_lds(                                     \
      (const __attribute__((address_space(1))) void*)(g),               \
      (__attribute__((address_space(3))) void*)(l), 16, 0, 0)

// ---------------- LayerNorm -> bf16 ----------------
__global__ __launch_bounds__(256) void ln_bf16_kernel(
    const float* __restrict__ x, const float* __restrict__ w,
    const float* __restrict__ b, unsigned short* __restrict__ o) {
  int row = blockIdx.x;
  int t = threadIdx.x;
  float v = x[(size_t)row * kC + t];
  float s = v, s2 = v * v;
#pragma unroll
  for (int off = 32; off > 0; off >>= 1) {
    s  += __shfl_down(s, off, 64);
    s2 += __shfl_down(s2, off, 64);
  }
  __shared__ float rs[4], rs2[4];
  __shared__ float mu_s, rstd_s;
  if ((t & 63) == 0) { rs[t >> 6] = s; rs2[t >> 6] = s2; }
  __syncthreads();
  if (t == 0) {
    float tot  = rs[0] + rs[1] + rs[2] + rs[3];
    float tot2 = rs2[0] + rs2[1] + rs2[2] + rs2[3];
    float mu  = tot * (1.0f / kC);
    float var = tot2 * (1.0f / kC) - mu * mu;
    mu_s = mu;
    rstd_s = rsqrtf(var + 1e-5f);
  }
  __syncthreads();
  o[(size_t)row * kC + t] = f2bf((v - mu_s) * rstd_s * w[t] + b[t]);
}

// ---------------- PE table ----------------
__global__ __launch_bounds__(256) void pe_kernel(const float* __restrict__ tab,
                                                 const float* __restrict__ pw,
                                                 const float* __restrict__ pb,
                                                 float* __restrict__ outp) {
  int i = blockIdx.x * 256 + threadIdx.x;
  if (i >= kTAB * 8) return;
  int r = i >> 3, h = i & 7;
  float acc = pb[h];
#pragma unroll
  for (int f = 0; f < 5; ++f) acc += tab[r * 5 + f] * pw[h * 5 + f];
  outp[i] = acc;
}

// ---------------- cast weights to bf16 (+ concat qkv bias) ----------------
__global__ __launch_bounds__(256) void cast_weights_kernel(
    const float* __restrict__ qw, const float* __restrict__ kvw,
    const float* __restrict__ pjw, const float* __restrict__ f1w,
    const float* __restrict__ f2w, const float* __restrict__ qb,
    const float* __restrict__ kvb, unsigned short* __restrict__ wqkv,
    unsigned short* __restrict__ wproj, unsigned short* __restrict__ wfc1,
    unsigned short* __restrict__ wfc2, float* __restrict__ bqkv) {
  int i = blockIdx.x * 256 + threadIdx.x;
  if (i < 65536)       wqkv[i]            = f2bf(qw[i]);
  else if (i < 196608) wqkv[i]            = f2bf(kvw[i - 65536]);
  else if (i < 262144) wproj[i - 196608]  = f2bf(pjw[i - 196608]);
  else if (i < 393216) wfc1[i - 262144]   = f2bf(f1w[i - 262144]);
  else if (i < 524288) wfc2[i - 393216]   = f2bf(f2w[i - 393216]);
  else if (i < 524544) bqkv[i - 524288]   = qb[i - 524288];
  else if (i < 525056) bqkv[i - 524288]   = kvb[i - 524544];
}

// ------- bf16 MFMA GEMM, 2-phase double-buffered LDS, fused epilogues -------
// 128x128 tile, 256 threads = 4 waves (2x2), 4x4 frags of 16x16x32 per wave.
// Per K-step: issue next tile's global_load_lds BEFORE computing current tile;
// ONE barrier per step (syncthreads drains vmcnt+lgkm).
// EPI 0: QKV (col<256 -> q bf16 *scale; else split k/v bf16)
// EPI 1: proj + residual -> f32;  EPI 2: fc1 + exact gelu -> bf16
// EPI 3: fc2 + residual -> f32
template <int EPI, int KDIM>
__global__ __launch_bounds__(256) void mfma_gemm(
    const unsigned short* __restrict__ A, const unsigned short* __restrict__ Wt,
    const float* __restrict__ bias, void* __restrict__ o1,
    unsigned short* __restrict__ o2, unsigned short* __restrict__ o3,
    const float* __restrict__ res) {
  __shared__ alignas(16) unsigned short As[2][128 * 32];
  __shared__ alignas(16) unsigned short Bs[2][128 * 32];
  int t = threadIdx.x;
  int w = t >> 6, l = t & 63;
  int wr = w >> 1, wc = w & 1;
  int bm = blockIdx.x * 128, bn = blockIdx.y * 128;

  f32x4 acc[4][4] = {};

  const size_t aoff = (size_t)(bm + w * 32 + (l >> 2)) * KDIM + (l & 3) * 8;
  const size_t boff = (size_t)(bn + w * 32 + (l >> 2)) * KDIM + (l & 3) * 8;
  const int ldsw = w * 1024 + l * 8;
  const int lr = l & 15, lk = l >> 4;

#define STAGE_T(buf, k0)                                                   \
  do {                                                                     \
    GLOAD16(A + aoff + (k0), &As[buf][ldsw]);                              \
    GLOAD16(A + aoff + (k0) + (size_t)16 * KDIM, &As[buf][ldsw + 512]);    \
    GLOAD16(Wt + boff + (k0), &Bs[buf][ldsw]);                             \
    GLOAD16(Wt + boff + (k0) + (size_t)16 * KDIM, &Bs[buf][ldsw + 512]);   \
  } while (0)

  auto compute = [&](int buf) {
    bf16x8 af[4], bfr[4];
#pragma unroll
    for (int mi = 0; mi < 4; ++mi)
      af[mi] =
          *(const bf16x8*)(&As[buf][(wr * 64 + mi * 16 + lr) * 32 + lk * 8]);
#pragma unroll
    for (int ni = 0; ni < 4; ++ni)
      bfr[ni] =
          *(const bf16x8*)(&Bs[buf][(wc * 64 + ni * 16 + lr) * 32 + lk * 8]);
#pragma unroll
    for (int mi = 0; mi < 4; ++mi)
#pragma unroll
      for (int ni = 0; ni < 4; ++ni)
        acc[mi][ni] = __builtin_amdgcn_mfma_f32_16x16x32_bf16(
            af[mi], bfr[ni], acc[mi][ni], 0, 0, 0);
  };

  STAGE_T(0, 0);
  __syncthreads();
  int cur = 0;
#pragma unroll
  for (int k0 = 32; k0 < KDIM; k0 += 32) {
    STAGE_T(cur ^ 1, k0);   // next tile's loads in flight during compute
    compute(cur);
    __syncthreads();        // drains this wave's vmcnt, then barrier
    cur ^= 1;
  }
  compute(cur);

  // epilogue: C/D layout col=lane&15, row=(lane>>4)*4+j
#pragma unroll
  for (int mi = 0; mi < 4; ++mi) {
#pragma unroll
    for (int ni = 0; ni < 4; ++ni) {
      int row0 = bm + wr * 64 + mi * 16 + lk * 4;
      int col  = bn + wc * 64 + ni * 16 + lr;
      float bv = bias[col];
#pragma unroll
      for (int j = 0; j < 4; ++j) {
        int r = row0 + j;
        float x = acc[mi][ni][j] + bv;
        if constexpr (EPI == 0) {
          if (col < 256) {
            ((unsigned short*)o1)[(size_t)r * 256 + col] = f2bf(x * kScale);
          } else {
            int c = col - 256;
            int h = c >> 6, sbit = (c >> 5) & 1, ch = c & 31;
            unsigned short* dst = sbit ? o3 : o2;
            dst[(size_t)r * 256 + h * 32 + ch] = f2bf(x);
          }
        } else if constexpr (EPI == 1) {
          ((float*)o1)[(size_t)r * 256 + col] = res[(size_t)r * 256 + col] + x;
        } else if constexpr (EPI == 2) {
          float g = 0.5f * x * (1.0f + erff(x * 0.70710678118654752f));
          ((unsigned short*)o1)[(size_t)r * 512 + col] = f2bf(g);
        } else {
          ((float*)o1)[(size_t)r * 256 + col] = res[(size_t)r * 256 + col] + x;
        }
      }
    }
  }
#undef STAGE_T
}

// ---------------- Attention: one WAVE per token (round-3 structure) -----------
// lane l: h = l>>3 (head), g = l&7. QK: 4 logits per lane (m = g+8*mi).
// PV: 4 output channels per lane (c = g*4..g*4+3) of head h.
__global__ __launch_bounds__(256) void attn_kernel(
    const unsigned short* __restrict__ q, const unsigned short* __restrict__ k,
    const unsigned short* __restrict__ v, const int* __restrict__ member_idx,
    const int* __restrict__ pe_idx, const float* __restrict__ cmask,
    const float* __restrict__ pe_full, const float* __restrict__ blank_k,
    const float* __restrict__ blank_v, unsigned short* __restrict__ outp) {
  int t = threadIdx.x;
  int w = t >> 6, l = t & 63;
  int row = blockIdx.x * 4 + w;
  int b = row >> 13;  // N = 8192
  const size_t kvbase = (size_t)b * kN;

  __shared__ float qs[4][8][36];   // [wave][head][ch], pad 36
  __shared__ float aw[4][8][40];   // attn weights, pad 40
  __shared__ int   idxs[4][32];
  __shared__ float mkb[4][32];
  __shared__ int   pei[4][32];

  // ---- stage q (bf16 -> f32) + indices ----
  {
    uint2 qu = *(const uint2*)(q + (size_t)row * 256 + l * 4);
    float4 qv4;
    qv4.x = bflo(qu.x); qv4.y = bfhi(qu.x);
    qv4.z = bflo(qu.y); qv4.w = bfhi(qu.y);
    *(float4*)&qs[w][l >> 3][(l & 7) * 4] = qv4;
    if (l < 32) {
      idxs[w][l] = member_idx[(size_t)row * 32 + l];
      mkb[w][l]  = (1.0f - cmask[(size_t)row * 32 + l]) * -100.0f;
      pei[w][l]  = pe_idx[(size_t)row * 32 + l];
    }
  }
  __syncthreads();

  const int h = l >> 3, g = l & 7;

  float4 qv[8];
#pragma unroll
  for (int i = 0; i < 8; ++i) qv[i] = *(const float4*)&qs[w][h][i * 4];

  // ---- QK logits: direct global K loads ----
  float lg[4];
#pragma unroll
  for (int mi = 0; mi < 4; ++mi) {
    int m = g + mi * 8;
    int idx = idxs[w][m];
    const unsigned short* kr = k + ((kvbase + idx) * 256 + h * 32);
    float acc = 0.f;
#pragma unroll
    for (int i = 0; i < 8; ++i) {
      uint2 u = *(const uint2*)(kr + i * 4);
      acc = fmaf(qv[i].x, bflo(u.x), acc);
      acc = fmaf(qv[i].y, bfhi(u.x), acc);
      acc = fmaf(qv[i].z, bflo(u.y), acc);
      acc = fmaf(qv[i].w, bfhi(u.y), acc);
    }
    lg[mi] = acc + mkb[w][m] + pe_full[(size_t)pei[w][m] * 8 + h];
  }

  // ---- blank logit (identical across the 8-lane head group) ----
  float bl = 0.f;
#pragma unroll
  for (int i = 0; i < 8; ++i) {
    float4 bk = *(const float4*)(blank_k + h * 32 + i * 4);
    bl += qv[i].x * bk.x + qv[i].y * bk.y + qv[i].z * bk.z + qv[i].w * bk.w;
  }
  bl = fminf(fmaxf(bl, -5.0f), 5.0f);

  // ---- wave-parallel softmax over 33 (8-lane group reduction) ----
  float mx = fmaxf(fmaxf(lg[0], lg[1]), fmaxf(lg[2], lg[3]));
#pragma unroll
  for (int d = 1; d < 8; d <<= 1) mx = fmaxf(mx, __shfl_xor(mx, d, 64));
  mx = fmaxf(mx, bl);
  float e[4], s = 0.f;
#pragma unroll
  for (int mi = 0; mi < 4; ++mi) { e[mi] = __expf(lg[mi] - mx); s += e[mi]; }
#pragma unroll
  for (int d = 1; d < 8; d <<= 1) s += __shfl_xor(s, d, 64);
  float eb = __expf(bl - mx);
  s += eb;
  float inv = __builtin_amdgcn_rcpf(s);
#pragma unroll
  for (int mi = 0; mi < 4; ++mi) aw[w][h][g + mi * 8] = e[mi] * inv;
  if (g == 0) aw[w][h][32] = eb * inv;
  __syncthreads();

  // ---- PV: direct global V loads, weights broadcast from LDS ----
  const int c0 = g * 4;
  const unsigned short* vbase = v + h * 32 + c0;
  float a0 = 0.f, a1 = 0.f, a2 = 0.f, a3 = 0.f;
#pragma unroll 8
  for (int m = 0; m < 32; ++m) {
    float a = aw[w][h][m];
    int idx = idxs[w][m];
    uint2 u = *(const uint2*)(vbase + (kvbase + idx) * 256);
    a0 = fmaf(a, bflo(u.x), a0);
    a1 = fmaf(a, bfhi(u.x), a1);
    a2 = fmaf(a, bflo(u.y), a2);
    a3 = fmaf(a, bfhi(u.y), a3);
  }
  {
    float ab = aw[w][h][32];
    float4 bv = *(const float4*)(blank_v + h * 32 + c0);
    a0 = fmaf(ab, bv.x, a0);
    a1 = fmaf(ab, bv.y, a1);
    a2 = fmaf(ab, bv.z, a2);
    a3 = fmaf(ab, bv.w, a3);
  }
  uint2 o;
  o.x = ((unsigned int)f2bf(a1) << 16) | f2bf(a0);
  o.y = ((unsigned int)f2bf(a3) << 16) | f2bf(a2);
  *(uint2*)(outp + (size_t)row * 256 + h * 32 + c0) = o;
}

extern "C" void kernel_launch(void* const* d_in, const int* in_sizes, int n_in,
                              void* d_out, int out_size, void* d_ws, size_t ws_size,
                              hipStream_t stream) {
  const float* feat       = (const float*)d_in[0];
  const int*   member_idx = (const int*)d_in[1];
  const float* cmask      = (const float*)d_in[2];
  const int*   pe_idx     = (const int*)d_in[3];
  const float* pre_table  = (const float*)d_in[5];
  const float* n1w        = (const float*)d_in[6];
  const float* n1b        = (const float*)d_in[7];
  const float* q_w        = (const float*)d_in[8];
  const float* q_b        = (const float*)d_in[9];
  const float* kv_w       = (const float*)d_in[10];
  const float* kv_b       = (const float*)d_in[11];
  const float* blank_k    = (const float*)d_in[12];
  const float* blank_v    = (const float*)d_in[13];
  const float* pe_w       = (const float*)d_in[14];
  const float* pe_b       = (const float*)d_in[15];
  const float* proj_w     = (const float*)d_in[16];
  const float* proj_b     = (const float*)d_in[17];
  const float* n2w        = (const float*)d_in[18];
  const float* n2b        = (const float*)d_in[19];
  const float* fc1_w      = (const float*)d_in[20];
  const float* fc1_b      = (const float*)d_in[21];
  const float* fc2_w      = (const float*)d_in[22];
  const float* fc2_b      = (const float*)d_in[23];

  float* out = (float*)d_out;
  unsigned char* ws = (unsigned char*)d_ws;

  unsigned short* xln   = (unsigned short*)(ws + 0);           // 8 MB, later attn_out
  unsigned short* q_buf = (unsigned short*)(ws + 8388608);     // 8 MB, later yln
  unsigned short* k_buf = (unsigned short*)(ws + 16777216);    // 8 MB \ later h1 (16MB)
  unsigned short* v_buf = (unsigned short*)(ws + 25165824);    // 8 MB /
  unsigned short* wqkv  = (unsigned short*)(ws + 33554432);    // 384 KB
  unsigned short* wproj = (unsigned short*)(ws + 33947648);    // 128 KB
  unsigned short* wfc1  = (unsigned short*)(ws + 34078720);    // 256 KB
  unsigned short* wfc2  = (unsigned short*)(ws + 34340864);    // 256 KB
  float*          bqkv  = (float*)(ws + 34603008);             // 3 KB
  float*          pe_buf= (float*)(ws + 34606080);             // ~97 KB
  unsigned short* attn_out = xln;
  unsigned short* yln   = q_buf;
  unsigned short* h1    = k_buf;   // 16 MB spanning k_buf+v_buf

  cast_weights_kernel<<<2052, 256, 0, stream>>>(
      q_w, kv_w, proj_w, fc1_w, fc2_w, q_b, kv_b, wqkv, wproj, wfc1, wfc2, bqkv);
  pe_kernel<<<(kTAB * 8 + 255) / 256, 256, 0, stream>>>(pre_table, pe_w, pe_b, pe_buf);
  ln_bf16_kernel<<<kRowsTotal, 256, 0, stream>>>(feat, n1w, n1b, xln);

  mfma_gemm<0, 256><<<dim3(kRowsTotal / 128, 6), 256, 0, stream>>>(
      xln, wqkv, bqkv, q_buf, k_buf, v_buf, nullptr);

  attn_kernel<<<kRowsTotal / 4, 256, 0, stream>>>(
      q_buf, k_buf, v_buf, member_idx, pe_idx, cmask, pe_buf, blank_k, blank_v,
      attn_out);

  mfma_gemm<1, 256><<<dim3(kRowsTotal / 128, 2), 256, 0, stream>>>(
      attn_out, wproj, proj_b, out, nullptr, nullptr, feat);

  ln_bf16_kernel<<<kRowsTotal, 256, 0, stream>>>(out, n2w, n2b, yln);

  mfma_gemm<2, 256><<<dim3(kRowsTotal / 128, 4), 256, 0, stream>>>(
      yln, wfc1, fc1_b, h1, nullptr, nullptr, nullptr);

  mfma_gemm<3, 512><<<dim3(kRowsTotal / 128, 2), 256, 0, stream>>>(
      h1, wfc2, fc2_b, out, nullptr, nullptr, out);
}

// Round 7
// 161.314 us; speedup vs baseline: 1.1149x; 1.1021x over previous
//
#include <hip/hip_runtime.h>
#include <math.h>

namespace {
constexpr int kN    = 8192;
constexpr int kC    = 256;
constexpr int kM    = 32;
constexpr int kTAB  = 3025;
constexpr int kRowsTotal = 2 * kN;  // B*N = 16384
constexpr float kScale = 0.17677669529663687f;  // 32^-0.5
}

typedef __attribute__((ext_vector_type(8))) short bf16x8;
typedef __attribute__((ext_vector_type(4))) float f32x4;

__device__ __forceinline__ unsigned short f2bf(float f) {
  unsigned int u = __float_as_uint(f);
  u += 0x7fffu + ((u >> 16) & 1u);   // round-to-nearest-even
  return (unsigned short)(u >> 16);
}
__device__ __forceinline__ float bflo(unsigned int u) {
  return __uint_as_float(u << 16);
}
__device__ __forceinline__ float bfhi(unsigned int u) {
  return __uint_as_float(u & 0xffff0000u);
}

#define GLOAD16(g, l)                                                   \
  __builtin_amdgcn_global_load_lds(                                     \
      (const __attribute__((address_space(1))) void*)(g),               \
      (__attribute__((address_space(3))) void*)(l), 16, 0, 0)

// ---------------- LayerNorm -> bf16 ----------------
__global__ __launch_bounds__(256) void ln_bf16_kernel(
    const float* __restrict__ x, const float* __restrict__ w,
    const float* __restrict__ b, unsigned short* __restrict__ o) {
  int row = blockIdx.x;
  int t = threadIdx.x;
  float v = x[(size_t)row * kC + t];
  float s = v, s2 = v * v;
#pragma unroll
  for (int off = 32; off > 0; off >>= 1) {
    s  += __shfl_down(s, off, 64);
    s2 += __shfl_down(s2, off, 64);
  }
  __shared__ float rs[4], rs2[4];
  __shared__ float mu_s, rstd_s;
  if ((t & 63) == 0) { rs[t >> 6] = s; rs2[t >> 6] = s2; }
  __syncthreads();
  if (t == 0) {
    float tot  = rs[0] + rs[1] + rs[2] + rs[3];
    float tot2 = rs2[0] + rs2[1] + rs2[2] + rs2[3];
    float mu  = tot * (1.0f / kC);
    float var = tot2 * (1.0f / kC) - mu * mu;
    mu_s = mu;
    rstd_s = rsqrtf(var + 1e-5f);
  }
  __syncthreads();
  o[(size_t)row * kC + t] = f2bf((v - mu_s) * rstd_s * w[t] + b[t]);
}

// ---------------- PE table ----------------
__global__ __launch_bounds__(256) void pe_kernel(const float* __restrict__ tab,
                                                 const float* __restrict__ pw,
                                                 const float* __restrict__ pb,
                                                 float* __restrict__ outp) {
  int i = blockIdx.x * 256 + threadIdx.x;
  if (i >= kTAB * 8) return;
  int r = i >> 3, h = i & 7;
  float acc = pb[h];
#pragma unroll
  for (int f = 0; f < 5; ++f) acc += tab[r * 5 + f] * pw[h * 5 + f];
  outp[i] = acc;
}

// ---------------- cast weights to bf16 (+ concat qkv bias) ----------------
__global__ __launch_bounds__(256) void cast_weights_kernel(
    const float* __restrict__ qw, const float* __restrict__ kvw,
    const float* __restrict__ pjw, const float* __restrict__ f1w,
    const float* __restrict__ f2w, const float* __restrict__ qb,
    const float* __restrict__ kvb, unsigned short* __restrict__ wqkv,
    unsigned short* __restrict__ wproj, unsigned short* __restrict__ wfc1,
    unsigned short* __restrict__ wfc2, float* __restrict__ bqkv) {
  int i = blockIdx.x * 256 + threadIdx.x;
  if (i < 65536)       wqkv[i]            = f2bf(qw[i]);
  else if (i < 196608) wqkv[i]            = f2bf(kvw[i - 65536]);
  else if (i < 262144) wproj[i - 196608]  = f2bf(pjw[i - 196608]);
  else if (i < 393216) wfc1[i - 262144]   = f2bf(f1w[i - 262144]);
  else if (i < 524288) wfc2[i - 393216]   = f2bf(f2w[i - 393216]);
  else if (i < 524544) bqkv[i - 524288]   = qb[i - 524288];
  else if (i < 525056) bqkv[i - 524288]   = kvb[i - 524544];
}

// ------- bf16 MFMA GEMM, BK=64 double-buffered LDS, fused epilogues -------
// 128x128 tile, 256 threads = 4 waves (2x2), 4x4 frags of 16x16x32 per wave.
// Per K-step (64 wide): stage next buffer BEFORE computing current; one
// barrier per step. Fragment ds_reads are bank-uniform (8 words/bank).
template <int EPI, int KDIM>
__global__ __launch_bounds__(256) void mfma_gemm(
    const unsigned short* __restrict__ A, const unsigned short* __restrict__ Wt,
    const float* __restrict__ bias, void* __restrict__ o1,
    unsigned short* __restrict__ o2, unsigned short* __restrict__ o3,
    const float* __restrict__ res) {
  __shared__ alignas(16) unsigned short As[2][128 * 64];
  __shared__ alignas(16) unsigned short Bs[2][128 * 64];
  int t = threadIdx.x;
  int w = t >> 6, l = t & 63;
  int wr = w >> 1, wc = w & 1;
  int bm = blockIdx.x * 128, bn = blockIdx.y * 128;

  f32x4 acc[4][4] = {};

  // staging: wave w rows w*32..w*32+31; instr i covers 8 rows; lane l ->
  // row w*32+i*8+(l>>3), elems (l&7)*8. LDS dest linear: base + l*16B.
  const size_t aoff = (size_t)(bm + w * 32 + (l >> 3)) * KDIM + (l & 7) * 8;
  const size_t boff = (size_t)(bn + w * 32 + (l >> 3)) * KDIM + (l & 7) * 8;
  const int ldsw = w * 2048 + l * 8;
  const int lr = l & 15, lk = l >> 4;

#define STAGE_T(buf, k0)                                                     \
  do {                                                                       \
    GLOAD16(A + aoff + (k0), &As[buf][ldsw]);                                \
    GLOAD16(A + aoff + (k0) + (size_t)8 * KDIM,  &As[buf][ldsw + 512]);      \
    GLOAD16(A + aoff + (k0) + (size_t)16 * KDIM, &As[buf][ldsw + 1024]);     \
    GLOAD16(A + aoff + (k0) + (size_t)24 * KDIM, &As[buf][ldsw + 1536]);     \
    GLOAD16(Wt + boff + (k0), &Bs[buf][ldsw]);                               \
    GLOAD16(Wt + boff + (k0) + (size_t)8 * KDIM,  &Bs[buf][ldsw + 512]);     \
    GLOAD16(Wt + boff + (k0) + (size_t)16 * KDIM, &Bs[buf][ldsw + 1024]);    \
    GLOAD16(Wt + boff + (k0) + (size_t)24 * KDIM, &Bs[buf][ldsw + 1536]);    \
  } while (0)

  auto compute = [&](int buf) {
#pragma unroll
    for (int kk = 0; kk < 2; ++kk) {
      bf16x8 af[4], bfr[4];
#pragma unroll
      for (int mi = 0; mi < 4; ++mi)
        af[mi] = *(const bf16x8*)(&As[buf][(wr * 64 + mi * 16 + lr) * 64 +
                                           kk * 32 + lk * 8]);
#pragma unroll
      for (int ni = 0; ni < 4; ++ni)
        bfr[ni] = *(const bf16x8*)(&Bs[buf][(wc * 64 + ni * 16 + lr) * 64 +
                                            kk * 32 + lk * 8]);
#pragma unroll
      for (int mi = 0; mi < 4; ++mi)
#pragma unroll
        for (int ni = 0; ni < 4; ++ni)
          acc[mi][ni] = __builtin_amdgcn_mfma_f32_16x16x32_bf16(
              af[mi], bfr[ni], acc[mi][ni], 0, 0, 0);
    }
  };

  STAGE_T(0, 0);
  __syncthreads();
  int cur = 0;
#pragma unroll
  for (int k0 = 64; k0 < KDIM; k0 += 64) {
    STAGE_T(cur ^ 1, k0);   // next tile's loads in flight during compute
    compute(cur);
    __syncthreads();
    cur ^= 1;
  }
  compute(cur);

  // epilogue: C/D layout col=lane&15, row=(lane>>4)*4+j
#pragma unroll
  for (int mi = 0; mi < 4; ++mi) {
#pragma unroll
    for (int ni = 0; ni < 4; ++ni) {
      int row0 = bm + wr * 64 + mi * 16 + lk * 4;
      int col  = bn + wc * 64 + ni * 16 + lr;
      float bv = bias[col];
#pragma unroll
      for (int j = 0; j < 4; ++j) {
        int r = row0 + j;
        float x = acc[mi][ni][j] + bv;
        if constexpr (EPI == 0) {
          if (col < 256) {
            ((unsigned short*)o1)[(size_t)r * 256 + col] = f2bf(x * kScale);
          } else {
            int c = col - 256;
            int h = c >> 6, sbit = (c >> 5) & 1, ch = c & 31;
            unsigned short* dst = sbit ? o3 : o2;
            dst[(size_t)r * 256 + h * 32 + ch] = f2bf(x);
          }
        } else if constexpr (EPI == 1) {
          ((float*)o1)[(size_t)r * 256 + col] = res[(size_t)r * 256 + col] + x;
        } else if constexpr (EPI == 2) {
          float g = 0.5f * x * (1.0f + erff(x * 0.70710678118654752f));
          ((unsigned short*)o1)[(size_t)r * 512 + col] = f2bf(g);
        } else {
          ((float*)o1)[(size_t)r * 256 + col] = res[(size_t)r * 256 + col] + x;
        }
      }
    }
  }
#undef STAGE_T
}

// ---------------- Attention: one WAVE per token, batch->XCD partition ---------
// blockIdx swizzle: xcd = bid&7 (assumed round-robin); xcd 0-3 -> batch 0,
// xcd 4-7 -> batch 1. Halves each XCD's K/V working set (16 MB -> 8 MB).
// lane l: h = l>>3 (head), g = l&7. QK: 4 logits/lane. PV: 4 channels/lane.
__global__ __launch_bounds__(256) void attn_kernel(
    const unsigned short* __restrict__ q, const unsigned short* __restrict__ k,
    const unsigned short* __restrict__ v, const int* __restrict__ member_idx,
    const int* __restrict__ pe_idx, const float* __restrict__ cmask,
    const float* __restrict__ pe_full, const float* __restrict__ blank_k,
    const float* __restrict__ blank_v, unsigned short* __restrict__ outp) {
  int t = threadIdx.x;
  int w = t >> 6, l = t & 63;
  // ---- batch-partition swizzle (bijective over 4096 blocks) ----
  int bid = blockIdx.x;
  int xcd = bid & 7;
  int j   = bid >> 3;                    // 0..511
  int bb  = xcd >> 2;                    // batch
  int tb  = (xcd & 3) * 512 + j;         // token-block within batch, 0..2047
  int row = bb * kN + tb * 4 + w;
  const size_t kvbase = (size_t)bb * kN;

  __shared__ float qs[4][8][36];   // [wave][head][ch], pad 36
  __shared__ float aw[4][8][40];   // attn weights, pad 40
  __shared__ int   idxs[4][32];
  __shared__ float mkb[4][32];
  __shared__ int   pei[4][32];

  // ---- stage q (bf16 -> f32) + indices ----
  {
    uint2 qu = *(const uint2*)(q + (size_t)row * 256 + l * 4);
    float4 qv4;
    qv4.x = bflo(qu.x); qv4.y = bfhi(qu.x);
    qv4.z = bflo(qu.y); qv4.w = bfhi(qu.y);
    *(float4*)&qs[w][l >> 3][(l & 7) * 4] = qv4;
    if (l < 32) {
      idxs[w][l] = member_idx[(size_t)row * 32 + l];
      mkb[w][l]  = (1.0f - cmask[(size_t)row * 32 + l]) * -100.0f;
      pei[w][l]  = pe_idx[(size_t)row * 32 + l];
    }
  }
  __syncthreads();

  const int h = l >> 3, g = l & 7;

  float4 qv[8];
#pragma unroll
  for (int i = 0; i < 8; ++i) qv[i] = *(const float4*)&qs[w][h][i * 4];

  // ---- QK logits: direct global K loads ----
  float lg[4];
#pragma unroll
  for (int mi = 0; mi < 4; ++mi) {
    int m = g + mi * 8;
    int idx = idxs[w][m];
    const unsigned short* kr = k + ((kvbase + idx) * 256 + h * 32);
    float acc = 0.f;
#pragma unroll
    for (int i = 0; i < 8; ++i) {
      uint2 u = *(const uint2*)(kr + i * 4);
      acc = fmaf(qv[i].x, bflo(u.x), acc);
      acc = fmaf(qv[i].y, bfhi(u.x), acc);
      acc = fmaf(qv[i].z, bflo(u.y), acc);
      acc = fmaf(qv[i].w, bfhi(u.y), acc);
    }
    lg[mi] = acc + mkb[w][m] + pe_full[(size_t)pei[w][m] * 8 + h];
  }

  // ---- blank logit (identical across the 8-lane head group) ----
  float bl = 0.f;
#pragma unroll
  for (int i = 0; i < 8; ++i) {
    float4 bk = *(const float4*)(blank_k + h * 32 + i * 4);
    bl += qv[i].x * bk.x + qv[i].y * bk.y + qv[i].z * bk.z + qv[i].w * bk.w;
  }
  bl = fminf(fmaxf(bl, -5.0f), 5.0f);

  // ---- wave-parallel softmax over 33 (8-lane group reduction) ----
  float mx = fmaxf(fmaxf(lg[0], lg[1]), fmaxf(lg[2], lg[3]));
#pragma unroll
  for (int d = 1; d < 8; d <<= 1) mx = fmaxf(mx, __shfl_xor(mx, d, 64));
  mx = fmaxf(mx, bl);
  float e[4], s = 0.f;
#pragma unroll
  for (int mi = 0; mi < 4; ++mi) { e[mi] = __expf(lg[mi] - mx); s += e[mi]; }
#pragma unroll
  for (int d = 1; d < 8; d <<= 1) s += __shfl_xor(s, d, 64);
  float eb = __expf(bl - mx);
  s += eb;
  float inv = __builtin_amdgcn_rcpf(s);
#pragma unroll
  for (int mi = 0; mi < 4; ++mi) aw[w][h][g + mi * 8] = e[mi] * inv;
  if (g == 0) aw[w][h][32] = eb * inv;
  __syncthreads();

  // ---- PV: direct global V loads, weights broadcast from LDS ----
  const int c0 = g * 4;
  const unsigned short* vbase = v + h * 32 + c0;
  float a0 = 0.f, a1 = 0.f, a2 = 0.f, a3 = 0.f;
#pragma unroll 8
  for (int m = 0; m < 32; ++m) {
    float a = aw[w][h][m];
    int idx = idxs[w][m];
    uint2 u = *(const uint2*)(vbase + (kvbase + idx) * 256);
    a0 = fmaf(a, bflo(u.x), a0);
    a1 = fmaf(a, bfhi(u.x), a1);
    a2 = fmaf(a, bflo(u.y), a2);
    a3 = fmaf(a, bfhi(u.y), a3);
  }
  {
    float ab = aw[w][h][32];
    float4 bv = *(const float4*)(blank_v + h * 32 + c0);
    a0 = fmaf(ab, bv.x, a0);
    a1 = fmaf(ab, bv.y, a1);
    a2 = fmaf(ab, bv.z, a2);
    a3 = fmaf(ab, bv.w, a3);
  }
  uint2 o;
  o.x = ((unsigned int)f2bf(a1) << 16) | f2bf(a0);
  o.y = ((unsigned int)f2bf(a3) << 16) | f2bf(a2);
  *(uint2*)(outp + (size_t)row * 256 + h * 32 + c0) = o;
}

extern "C" void kernel_launch(void* const* d_in, const int* in_sizes, int n_in,
                              void* d_out, int out_size, void* d_ws, size_t ws_size,
                              hipStream_t stream) {
  const float* feat       = (const float*)d_in[0];
  const int*   member_idx = (const int*)d_in[1];
  const float* cmask      = (const float*)d_in[2];
  const int*   pe_idx     = (const int*)d_in[3];
  const float* pre_table  = (const float*)d_in[5];
  const float* n1w        = (const float*)d_in[6];
  const float* n1b        = (const float*)d_in[7];
  const float* q_w        = (const float*)d_in[8];
  const float* q_b        = (const float*)d_in[9];
  const float* kv_w       = (const float*)d_in[10];
  const float* kv_b       = (const float*)d_in[11];
  const float* blank_k    = (const float*)d_in[12];
  const float* blank_v    = (const float*)d_in[13];
  const float* pe_w       = (const float*)d_in[14];
  const float* pe_b       = (const float*)d_in[15];
  const float* proj_w     = (const float*)d_in[16];
  const float* proj_b     = (const float*)d_in[17];
  const float* n2w        = (const float*)d_in[18];
  const float* n2b        = (const float*)d_in[19];
  const float* fc1_w      = (const float*)d_in[20];
  const float* fc1_b      = (const float*)d_in[21];
  const float* fc2_w      = (const float*)d_in[22];
  const float* fc2_b      = (const float*)d_in[23];

  float* out = (float*)d_out;
  unsigned char* ws = (unsigned char*)d_ws;

  unsigned short* xln   = (unsigned short*)(ws + 0);           // 8 MB, later attn_out
  unsigned short* q_buf = (unsigned short*)(ws + 8388608);     // 8 MB, later yln
  unsigned short* k_buf = (unsigned short*)(ws + 16777216);    // 8 MB \ later h1 (16MB)
  unsigned short* v_buf = (unsigned short*)(ws + 25165824);    // 8 MB /
  unsigned short* wqkv  = (unsigned short*)(ws + 33554432);    // 384 KB
  unsigned short* wproj = (unsigned short*)(ws + 33947648);    // 128 KB
  unsigned short* wfc1  = (unsigned short*)(ws + 34078720);    // 256 KB
  unsigned short* wfc2  = (unsigned short*)(ws + 34340864);    // 256 KB
  float*          bqkv  = (float*)(ws + 34603008);             // 3 KB
  float*          pe_buf= (float*)(ws + 34606080);             // ~97 KB
  unsigned short* attn_out = xln;
  unsigned short* yln   = q_buf;
  unsigned short* h1    = k_buf;   // 16 MB spanning k_buf+v_buf

  cast_weights_kernel<<<2052, 256, 0, stream>>>(
      q_w, kv_w, proj_w, fc1_w, fc2_w, q_b, kv_b, wqkv, wproj, wfc1, wfc2, bqkv);
  pe_kernel<<<(kTAB * 8 + 255) / 256, 256, 0, stream>>>(pre_table, pe_w, pe_b, pe_buf);
  ln_bf16_kernel<<<kRowsTotal, 256, 0, stream>>>(feat, n1w, n1b, xln);

  mfma_gemm<0, 256><<<dim3(kRowsTotal / 128, 6), 256, 0, stream>>>(
      xln, wqkv, bqkv, q_buf, k_buf, v_buf, nullptr);

  attn_kernel<<<kRowsTotal / 4, 256, 0, stream>>>(
      q_buf, k_buf, v_buf, member_idx, pe_idx, cmask, pe_buf, blank_k, blank_v,
      attn_out);

  mfma_gemm<1, 256><<<dim3(kRowsTotal / 128, 2), 256, 0, stream>>>(
      attn_out, wproj, proj_b, out, nullptr, nullptr, feat);

  ln_bf16_kernel<<<kRowsTotal, 256, 0, stream>>>(out, n2w, n2b, yln);

  mfma_gemm<2, 256><<<dim3(kRowsTotal / 128, 4), 256, 0, stream>>>(
      yln, wfc1, fc1_b, h1, nullptr, nullptr, nullptr);

  mfma_gemm<3, 512><<<dim3(kRowsTotal / 128, 2), 256, 0, stream>>>(
      h1, wfc2, fc2_b, out, nullptr, nullptr, out);
}

// Round 8
// 134.689 us; speedup vs baseline: 1.3353x; 1.1977x over previous
//
#include <hip/hip_runtime.h>
#include <math.h>

namespace {
constexpr int kN    = 8192;
constexpr int kC    = 256;
constexpr int kTAB  = 3025;
constexpr int kRowsTotal = 2 * kN;  // B*N = 16384
constexpr float kScale = 0.17677669529663687f;  // 32^-0.5
}

typedef __attribute__((ext_vector_type(8))) short bf16x8;
typedef __attribute__((ext_vector_type(4))) float f32x4;

__device__ __forceinline__ unsigned short f2bf(float f) {
  unsigned int u = __float_as_uint(f);
  u += 0x7fffu + ((u >> 16) & 1u);   // round-to-nearest-even
  return (unsigned short)(u >> 16);
}
__device__ __forceinline__ float bflo(unsigned int u) {
  return __uint_as_float(u << 16);
}
__device__ __forceinline__ float bfhi(unsigned int u) {
  return __uint_as_float(u & 0xffff0000u);
}

#define GLOAD16(g, l)                                                   \
  __builtin_amdgcn_global_load_lds(                                     \
      (const __attribute__((address_space(1))) void*)(g),               \
      (__attribute__((address_space(3))) void*)(l), 16, 0, 0)

// ---------------- LayerNorm -> bf16 (wave per row, no barriers) --------------
__global__ __launch_bounds__(256) void ln_bf16_kernel(
    const float* __restrict__ x, const float* __restrict__ w,
    const float* __restrict__ b, unsigned short* __restrict__ o) {
  int t = threadIdx.x;
  int row = blockIdx.x * 4 + (t >> 6);
  int l = t & 63;
  float4 v = *(const float4*)(x + (size_t)row * kC + l * 4);
  float s  = v.x + v.y + v.z + v.w;
  float s2 = v.x * v.x + v.y * v.y + v.z * v.z + v.w * v.w;
#pragma unroll
  for (int d = 1; d < 64; d <<= 1) {
    s  += __shfl_xor(s, d, 64);
    s2 += __shfl_xor(s2, d, 64);
  }
  float mu = s * (1.0f / kC);
  float rstd = rsqrtf(s2 * (1.0f / kC) - mu * mu + 1e-5f);
  float4 wv = *(const float4*)(w + l * 4);
  float4 bv = *(const float4*)(b + l * 4);
  unsigned short o0 = f2bf((v.x - mu) * rstd * wv.x + bv.x);
  unsigned short o1 = f2bf((v.y - mu) * rstd * wv.y + bv.y);
  unsigned short o2 = f2bf((v.z - mu) * rstd * wv.z + bv.z);
  unsigned short o3 = f2bf((v.w - mu) * rstd * wv.w + bv.w);
  uint2 ov;
  ov.x = ((unsigned int)o1 << 16) | o0;
  ov.y = ((unsigned int)o3 << 16) | o2;
  *(uint2*)(o + (size_t)row * kC + l * 4) = ov;
}

// ---------------- PE table ----------------
__global__ __launch_bounds__(256) void pe_kernel(const float* __restrict__ tab,
                                                 const float* __restrict__ pw,
                                                 const float* __restrict__ pb,
                                                 float* __restrict__ outp) {
  int i = blockIdx.x * 256 + threadIdx.x;
  if (i >= kTAB * 8) return;
  int r = i >> 3, h = i & 7;
  float acc = pb[h];
#pragma unroll
  for (int f = 0; f < 5; ++f) acc += tab[r * 5 + f] * pw[h * 5 + f];
  outp[i] = acc;
}

// ---------------- cast weights to bf16 (+ concat qkv bias) ----------------
__global__ __launch_bounds__(256) void cast_weights_kernel(
    const float* __restrict__ qw, const float* __restrict__ kvw,
    const float* __restrict__ pjw, const float* __restrict__ f1w,
    const float* __restrict__ f2w, const float* __restrict__ qb,
    const float* __restrict__ kvb, unsigned short* __restrict__ wqkv,
    unsigned short* __restrict__ wproj, unsigned short* __restrict__ wfc1,
    unsigned short* __restrict__ wfc2, float* __restrict__ bqkv) {
  int i = blockIdx.x * 256 + threadIdx.x;
  if (i < 65536)       wqkv[i]            = f2bf(qw[i]);
  else if (i < 196608) wqkv[i]            = f2bf(kvw[i - 65536]);
  else if (i < 262144) wproj[i - 196608]  = f2bf(pjw[i - 196608]);
  else if (i < 393216) wfc1[i - 262144]   = f2bf(f1w[i - 262144]);
  else if (i < 524288) wfc2[i - 393216]   = f2bf(f2w[i - 393216]);
  else if (i < 524544) bqkv[i - 524288]   = qb[i - 524288];
  else if (i < 525056) bqkv[i - 524288]   = kvb[i - 524544];
}

// ---- bf16 MFMA GEMM: BM=64, BN=256, 8 waves (512 thr), BK=64 double-buffer --
// Wave w owns output cols w*32..w*32+31 (ni=0..1 16-col frags), rows 0..63
// (mi=0..3). Per K-step: stage next buffer first, one barrier per step.
// EPI 0: QKV (global col<256 -> q bf16 *scale; else k/v split bf16)
// EPI 1: proj + residual(feat) -> x f32 AND fused LN2 -> yln bf16
// EPI 2: fc1 + exact gelu -> bf16 (ld 512)
// EPI 3: fc2 + residual -> f32
template <int EPI, int KDIM>
__global__ __launch_bounds__(512) void gemm64(
    const unsigned short* __restrict__ A, const unsigned short* __restrict__ Wt,
    const float* __restrict__ bias, void* __restrict__ o1,
    unsigned short* __restrict__ o2, unsigned short* __restrict__ o3,
    const float* __restrict__ res, const float* __restrict__ w2,
    const float* __restrict__ b2, unsigned short* __restrict__ yln) {
  // LDS: As[2][64*64] (8KB each), Bs[2][256*64] (32KB each) = 80KB total.
  // After the K-loop (EPI==1) the same LDS is reused as x-tile f32 [64][260].
  __shared__ alignas(16) unsigned short smem[40960];
  unsigned short* As0 = smem;
  unsigned short* Bs0 = smem + 8192;
  int t = threadIdx.x;
  int w = t >> 6, l = t & 63;
  int bm = blockIdx.x * 64, bn = blockIdx.y * 256;

  f32x4 acc[4][2] = {};

  const size_t aoff = (size_t)(bm + w * 8 + (l >> 3)) * KDIM + (l & 7) * 8;
  const size_t boff = (size_t)(bn + w * 32 + (l >> 3)) * KDIM + (l & 7) * 8;
  const int lr = l & 15, lk = l >> 4;

#define STAGE_T(buf, k0)                                                      \
  do {                                                                        \
    GLOAD16(A + aoff + (k0), As0 + (buf)*4096 + w * 512 + l * 8);             \
    GLOAD16(Wt + boff + (k0), Bs0 + (buf)*16384 + w * 2048 + l * 8);          \
    GLOAD16(Wt + boff + (k0) + (size_t)8 * KDIM,                              \
            Bs0 + (buf)*16384 + w * 2048 + 512 + l * 8);                      \
    GLOAD16(Wt + boff + (k0) + (size_t)16 * KDIM,                             \
            Bs0 + (buf)*16384 + w * 2048 + 1024 + l * 8);                     \
    GLOAD16(Wt + boff + (k0) + (size_t)24 * KDIM,                             \
            Bs0 + (buf)*16384 + w * 2048 + 1536 + l * 8);                     \
  } while (0)

  auto compute = [&](int buf) {
#pragma unroll
    for (int kk = 0; kk < 2; ++kk) {
      bf16x8 af[4], bfr[2];
#pragma unroll
      for (int mi = 0; mi < 4; ++mi)
        af[mi] = *(const bf16x8*)(As0 + buf * 4096 + (mi * 16 + lr) * 64 +
                                  kk * 32 + lk * 8);
#pragma unroll
      for (int ni = 0; ni < 2; ++ni)
        bfr[ni] = *(const bf16x8*)(Bs0 + buf * 16384 +
                                   (w * 32 + ni * 16 + lr) * 64 + kk * 32 +
                                   lk * 8);
#pragma unroll
      for (int mi = 0; mi < 4; ++mi)
#pragma unroll
        for (int ni = 0; ni < 2; ++ni)
          acc[mi][ni] = __builtin_amdgcn_mfma_f32_16x16x32_bf16(
              af[mi], bfr[ni], acc[mi][ni], 0, 0, 0);
    }
  };

  STAGE_T(0, 0);
  __syncthreads();
  int cur = 0;
#pragma unroll
  for (int k0 = 64; k0 < KDIM; k0 += 64) {
    STAGE_T(cur ^ 1, k0);
    compute(cur);
    __syncthreads();
    cur ^= 1;
  }
  compute(cur);

  // ---------------- epilogues ----------------
  if constexpr (EPI == 1) {
    // proj + residual -> x (f32 global + LDS tile), then fused LN2 -> yln
    __syncthreads();   // all waves done reading tiles; reuse LDS as x[64][260]
    float* xs = (float*)smem;
#pragma unroll
    for (int mi = 0; mi < 4; ++mi) {
#pragma unroll
      for (int ni = 0; ni < 2; ++ni) {
        int c = w * 32 + ni * 16 + lr;
        float bv = bias[c];
#pragma unroll
        for (int j = 0; j < 4; ++j) {
          int rl = mi * 16 + lk * 4 + j;
          float x = acc[mi][ni][j] + bv + res[(size_t)(bm + rl) * 256 + c];
          xs[rl * 260 + c] = x;
          ((float*)o1)[(size_t)(bm + rl) * 256 + c] = x;
        }
      }
    }
    __syncthreads();
    // LN pass: 8 threads per row; thread sub handles cols sub*4 + i*32
    int r = t >> 3, sub = t & 7;
    float4 xv[8];
    float sx = 0.f, sxx = 0.f;
#pragma unroll
    for (int i = 0; i < 8; ++i) {
      xv[i] = *(const float4*)&xs[r * 260 + sub * 4 + i * 32];
      sx  += xv[i].x + xv[i].y + xv[i].z + xv[i].w;
      sxx += xv[i].x * xv[i].x + xv[i].y * xv[i].y + xv[i].z * xv[i].z +
             xv[i].w * xv[i].w;
    }
#pragma unroll
    for (int d = 1; d < 8; d <<= 1) {
      sx  += __shfl_xor(sx, d, 64);
      sxx += __shfl_xor(sxx, d, 64);
    }
    float mu = sx * (1.0f / 256.0f);
    float rstd = rsqrtf(sxx * (1.0f / 256.0f) - mu * mu + 1e-5f);
#pragma unroll
    for (int i = 0; i < 8; ++i) {
      int c = sub * 4 + i * 32;
      float4 wv = *(const float4*)(w2 + c);
      float4 bv = *(const float4*)(b2 + c);
      unsigned short y0 = f2bf((xv[i].x - mu) * rstd * wv.x + bv.x);
      unsigned short y1 = f2bf((xv[i].y - mu) * rstd * wv.y + bv.y);
      unsigned short y2 = f2bf((xv[i].z - mu) * rstd * wv.z + bv.z);
      unsigned short y3 = f2bf((xv[i].w - mu) * rstd * wv.w + bv.w);
      uint2 ov;
      ov.x = ((unsigned int)y1 << 16) | y0;
      ov.y = ((unsigned int)y3 << 16) | y2;
      *(uint2*)(yln + (size_t)(bm + r) * 256 + c) = ov;
    }
  } else {
#pragma unroll
    for (int mi = 0; mi < 4; ++mi) {
#pragma unroll
      for (int ni = 0; ni < 2; ++ni) {
        int col = bn + w * 32 + ni * 16 + lr;
        float bv = bias[col];
#pragma unroll
        for (int j = 0; j < 4; ++j) {
          int rg = bm + mi * 16 + lk * 4 + j;
          float x = acc[mi][ni][j] + bv;
          if constexpr (EPI == 0) {
            if (col < 256) {
              ((unsigned short*)o1)[(size_t)rg * 256 + col] = f2bf(x * kScale);
            } else {
              int c = col - 256;
              int h = c >> 6, sbit = (c >> 5) & 1, ch = c & 31;
              unsigned short* dst = sbit ? o3 : o2;
              dst[(size_t)rg * 256 + h * 32 + ch] = f2bf(x);
            }
          } else if constexpr (EPI == 2) {
            float g = 0.5f * x * (1.0f + erff(x * 0.70710678118654752f));
            ((unsigned short*)o1)[(size_t)rg * 512 + col] = f2bf(g);
          } else {
            ((float*)o1)[(size_t)rg * 256 + col] =
                res[(size_t)rg * 256 + col] + x;
          }
        }
      }
    }
  }
#undef STAGE_T
}

// ---------------- Attention: one WAVE per token (round-3 structure) -----------
__global__ __launch_bounds__(256) void attn_kernel(
    const unsigned short* __restrict__ q, const unsigned short* __restrict__ k,
    const unsigned short* __restrict__ v, const int* __restrict__ member_idx,
    const int* __restrict__ pe_idx, const float* __restrict__ cmask,
    const float* __restrict__ pe_full, const float* __restrict__ blank_k,
    const float* __restrict__ blank_v, unsigned short* __restrict__ outp) {
  int t = threadIdx.x;
  int w = t >> 6, l = t & 63;
  int bid = blockIdx.x;
  int xcd = bid & 7;
  int j   = bid >> 3;
  int bb  = xcd >> 2;
  int tb  = (xcd & 3) * 512 + j;
  int row = bb * kN + tb * 4 + w;
  const size_t kvbase = (size_t)bb * kN;

  __shared__ float qs[4][8][36];
  __shared__ float aw[4][8][40];
  __shared__ int   idxs[4][32];
  __shared__ float mkb[4][32];
  __shared__ int   pei[4][32];

  {
    uint2 qu = *(const uint2*)(q + (size_t)row * 256 + l * 4);
    float4 qv4;
    qv4.x = bflo(qu.x); qv4.y = bfhi(qu.x);
    qv4.z = bflo(qu.y); qv4.w = bfhi(qu.y);
    *(float4*)&qs[w][l >> 3][(l & 7) * 4] = qv4;
    if (l < 32) {
      idxs[w][l] = member_idx[(size_t)row * 32 + l];
      mkb[w][l]  = (1.0f - cmask[(size_t)row * 32 + l]) * -100.0f;
      pei[w][l]  = pe_idx[(size_t)row * 32 + l];
    }
  }
  __syncthreads();

  const int h = l >> 3, g = l & 7;

  float4 qv[8];
#pragma unroll
  for (int i = 0; i < 8; ++i) qv[i] = *(const float4*)&qs[w][h][i * 4];

  float lg[4];
#pragma unroll
  for (int mi = 0; mi < 4; ++mi) {
    int m = g + mi * 8;
    int idx = idxs[w][m];
    const unsigned short* kr = k + ((kvbase + idx) * 256 + h * 32);
    float acc = 0.f;
#pragma unroll
    for (int i = 0; i < 8; ++i) {
      uint2 u = *(const uint2*)(kr + i * 4);
      acc = fmaf(qv[i].x, bflo(u.x), acc);
      acc = fmaf(qv[i].y, bfhi(u.x), acc);
      acc = fmaf(qv[i].z, bflo(u.y), acc);
      acc = fmaf(qv[i].w, bfhi(u.y), acc);
    }
    lg[mi] = acc + mkb[w][m] + pe_full[(size_t)pei[w][m] * 8 + h];
  }

  float bl = 0.f;
#pragma unroll
  for (int i = 0; i < 8; ++i) {
    float4 bk = *(const float4*)(blank_k + h * 32 + i * 4);
    bl += qv[i].x * bk.x + qv[i].y * bk.y + qv[i].z * bk.z + qv[i].w * bk.w;
  }
  bl = fminf(fmaxf(bl, -5.0f), 5.0f);

  float mx = fmaxf(fmaxf(lg[0], lg[1]), fmaxf(lg[2], lg[3]));
#pragma unroll
  for (int d = 1; d < 8; d <<= 1) mx = fmaxf(mx, __shfl_xor(mx, d, 64));
  mx = fmaxf(mx, bl);
  float e[4], s = 0.f;
#pragma unroll
  for (int mi = 0; mi < 4; ++mi) { e[mi] = __expf(lg[mi] - mx); s += e[mi]; }
#pragma unroll
  for (int d = 1; d < 8; d <<= 1) s += __shfl_xor(s, d, 64);
  float eb = __expf(bl - mx);
  s += eb;
  float inv = __builtin_amdgcn_rcpf(s);
#pragma unroll
  for (int mi = 0; mi < 4; ++mi) aw[w][h][g + mi * 8] = e[mi] * inv;
  if (g == 0) aw[w][h][32] = eb * inv;
  __syncthreads();

  const int c0 = g * 4;
  const unsigned short* vbase = v + h * 32 + c0;
  float a0 = 0.f, a1 = 0.f, a2 = 0.f, a3 = 0.f;
#pragma unroll 8
  for (int m = 0; m < 32; ++m) {
    float a = aw[w][h][m];
    int idx = idxs[w][m];
    uint2 u = *(const uint2*)(vbase + (kvbase + idx) * 256);
    a0 = fmaf(a, bflo(u.x), a0);
    a1 = fmaf(a, bfhi(u.x), a1);
    a2 = fmaf(a, bflo(u.y), a2);
    a3 = fmaf(a, bfhi(u.y), a3);
  }
  {
    float ab = aw[w][h][32];
    float4 bv = *(const float4*)(blank_v + h * 32 + c0);
    a0 = fmaf(ab, bv.x, a0);
    a1 = fmaf(ab, bv.y, a1);
    a2 = fmaf(ab, bv.z, a2);
    a3 = fmaf(ab, bv.w, a3);
  }
  uint2 o;
  o.x = ((unsigned int)f2bf(a1) << 16) | f2bf(a0);
  o.y = ((unsigned int)f2bf(a3) << 16) | f2bf(a2);
  *(uint2*)(outp + (size_t)row * 256 + h * 32 + c0) = o;
}

extern "C" void kernel_launch(void* const* d_in, const int* in_sizes, int n_in,
                              void* d_out, int out_size, void* d_ws, size_t ws_size,
                              hipStream_t stream) {
  const float* feat       = (const float*)d_in[0];
  const int*   member_idx = (const int*)d_in[1];
  const float* cmask      = (const float*)d_in[2];
  const int*   pe_idx     = (const int*)d_in[3];
  const float* pre_table  = (const float*)d_in[5];
  const float* n1w        = (const float*)d_in[6];
  const float* n1b        = (const float*)d_in[7];
  const float* q_w        = (const float*)d_in[8];
  const float* q_b        = (const float*)d_in[9];
  const float* kv_w       = (const float*)d_in[10];
  const float* kv_b       = (const float*)d_in[11];
  const float* blank_k    = (const float*)d_in[12];
  const float* blank_v    = (const float*)d_in[13];
  const float* pe_w       = (const float*)d_in[14];
  const float* pe_b       = (const float*)d_in[15];
  const float* proj_w     = (const float*)d_in[16];
  const float* proj_b     = (const float*)d_in[17];
  const float* n2w        = (const float*)d_in[18];
  const float* n2b        = (const float*)d_in[19];
  const float* fc1_w      = (const float*)d_in[20];
  const float* fc1_b      = (const float*)d_in[21];
  const float* fc2_w      = (const float*)d_in[22];
  const float* fc2_b      = (const float*)d_in[23];

  float* out = (float*)d_out;
  unsigned char* ws = (unsigned char*)d_ws;

  unsigned short* xln   = (unsigned short*)(ws + 0);           // 8 MB, later attn_out
  unsigned short* q_buf = (unsigned short*)(ws + 8388608);     // 8 MB, later yln
  unsigned short* k_buf = (unsigned short*)(ws + 16777216);    // 8 MB \ later h1 (16MB)
  unsigned short* v_buf = (unsigned short*)(ws + 25165824);    // 8 MB /
  unsigned short* wqkv  = (unsigned short*)(ws + 33554432);    // 384 KB
  unsigned short* wproj = (unsigned short*)(ws + 33947648);    // 128 KB
  unsigned short* wfc1  = (unsigned short*)(ws + 34078720);    // 256 KB
  unsigned short* wfc2  = (unsigned short*)(ws + 34340864);    // 256 KB
  float*          bqkv  = (float*)(ws + 34603008);             // 3 KB
  float*          pe_buf= (float*)(ws + 34606080);             // ~97 KB
  unsigned short* attn_out = xln;
  unsigned short* yln   = q_buf;
  unsigned short* h1    = k_buf;   // 16 MB spanning k_buf+v_buf

  cast_weights_kernel<<<2052, 256, 0, stream>>>(
      q_w, kv_w, proj_w, fc1_w, fc2_w, q_b, kv_b, wqkv, wproj, wfc1, wfc2, bqkv);
  pe_kernel<<<(kTAB * 8 + 255) / 256, 256, 0, stream>>>(pre_table, pe_w, pe_b, pe_buf);
  ln_bf16_kernel<<<kRowsTotal / 4, 256, 0, stream>>>(feat, n1w, n1b, xln);

  // QKV: [16384 x 768]; col-blocks of 256 (A panel read 3x)
  gemm64<0, 256><<<dim3(kRowsTotal / 64, 3), 512, 0, stream>>>(
      xln, wqkv, bqkv, q_buf, k_buf, v_buf, nullptr, nullptr, nullptr, nullptr);

  attn_kernel<<<kRowsTotal / 4, 256, 0, stream>>>(
      q_buf, k_buf, v_buf, member_idx, pe_idx, cmask, pe_buf, blank_k, blank_v,
      attn_out);

  // proj + residual -> x (f32, d_out) with fused LN2 -> yln (bf16)
  gemm64<1, 256><<<dim3(kRowsTotal / 64, 1), 512, 0, stream>>>(
      attn_out, wproj, proj_b, out, nullptr, nullptr, feat, n2w, n2b, yln);

  // fc1 + gelu -> h1 (bf16, ld 512)
  gemm64<2, 256><<<dim3(kRowsTotal / 64, 2), 512, 0, stream>>>(
      yln, wfc1, fc1_b, h1, nullptr, nullptr, nullptr, nullptr, nullptr, nullptr);

  // fc2 + residual(x) -> out (f32, in-place over d_out)
  gemm64<3, 512><<<dim3(kRowsTotal / 64, 1), 512, 0, stream>>>(
      h1, wfc2, fc2_b, out, nullptr, nullptr, out, nullptr, nullptr, nullptr);
}